// Round 7
// baseline (551.495 us; speedup 1.0000x reference)
//
#include <hip/hip_runtime.h>
#include <stdint.h>

// GraphConvolution: out[0:8192]    = deg[i]     *(adj  @ (v@Wv)) + bias
//                   out[8192:16k]  = deg[8192+j]*(adjT @ (u@Wu)) + bias
// R7 (530us): fused 256x256 tiles, 2-phase barriers -> all pipes idle,
// 2.1 TB/s (phase serialization: __syncthreads drains vmcnt; no reads in
// flight during compute). R9: same verified math, pipelined:
//  - panels 32x256, DOUBLE-buffered LDS (32KB), 8 panels/tile
//  - loads for panel p+1 issued BEFORE the barrier (stay in flight)
//  - raw s_barrier + lgkmcnt(0) only (vmcnt never drained in loop)
//  - ONE barrier per panel (safe: writes of p+2 hit buf p&1 only after
//    barrier(p+1), which waits for compute(p) readers)
// (R10 = R9 resubmitted unchanged: rounds 4 and 6 both died on GPU
// acquisition timeout; R9 has never been measured.)

#define HID 64
#define IN_DIM 128
#define NROWS 8192
#define NCLS 5

typedef float f32x4 __attribute__((ext_vector_type(4)));
typedef short s16x8 __attribute__((ext_vector_type(8)));
typedef short s16x4 __attribute__((ext_vector_type(4)));
typedef unsigned short u16;

// packed side size: 256 kb * 4 nb * 64 lane * 8 e = 524288 u16 = 1 MiB
#define PACK_SIDE 524288

static __device__ __forceinline__ short f2b(float x) {  // RNE fp32->bf16
    unsigned u = __builtin_bit_cast(unsigned, x);
    return (short)((u + 0x7FFFu + ((u >> 16) & 1u)) >> 16);
}

// ---------------------------------------------------------------------------
// k_prep: W = sum_{c<=r} weight[c]; s = X @ W; store B-fragment-packed bf16:
// pack[kb][nb][lane][e] = s[row = kb*32 + (lane>>4)*8 + e][h = nb*16 + (lane&15)]
// grid (128, 2): y=0 -> pu (from u), y=1 -> pv (from v). block 256.
// ---------------------------------------------------------------------------
__global__ __launch_bounds__(256, 2) void k_prep(
    const float* __restrict__ u, const float* __restrict__ v,
    const float* __restrict__ uw, const float* __restrict__ vw,
    const int* __restrict__ rp, u16* __restrict__ ws)
{
    __shared__ float W[IN_DIM * HID];
    __shared__ float X[64 * 129];

    const int y = blockIdx.y;
    const float* __restrict__ src  = y ? v  : u;
    const float* __restrict__ wsrc = y ? vw : uw;
    u16* __restrict__ dstP = ws + (size_t)y * PACK_SIDE;
    const int i0 = blockIdx.x * 64;
    const int t = threadIdx.x;
    int r = *rp; if (r > NCLS - 1) r = NCLS - 1; if (r < 0) r = 0;

    for (int idx = t; idx < IN_DIM * HID; idx += 256) {
        float s = 0.f;
        for (int c = 0; c <= r; ++c) s += wsrc[c * (IN_DIM * HID) + idx];
        W[idx] = s;
    }
    #pragma unroll
    for (int qq = 0; qq < 8; ++qq) {       // 64 rows x 32 float4 = 2048
        int idx = t + qq * 256;
        int row = idx >> 5, c4 = idx & 31;
        f32x4 val = *(const f32x4*)&src[(size_t)(i0 + row) * IN_DIM + c4 * 4];
        float* d = &X[row * 129 + c4 * 4];
        d[0] = val[0]; d[1] = val[1]; d[2] = val[2]; d[3] = val[3];
    }
    __syncthreads();

    const int i = t & 63, h0 = (t >> 6) * 16;
    float acc[16];
    #pragma unroll
    for (int k = 0; k < 16; ++k) acc[k] = 0.f;
    for (int c = 0; c < IN_DIM; ++c) {
        float uv = X[i * 129 + c];
        const f32x4* wr = (const f32x4*)&W[c * HID + h0];
        f32x4 w0 = wr[0], w1 = wr[1], w2 = wr[2], w3 = wr[3];
        acc[0]  += uv * w0[0]; acc[1]  += uv * w0[1];
        acc[2]  += uv * w0[2]; acc[3]  += uv * w0[3];
        acc[4]  += uv * w1[0]; acc[5]  += uv * w1[1];
        acc[6]  += uv * w1[2]; acc[7]  += uv * w1[3];
        acc[8]  += uv * w2[0]; acc[9]  += uv * w2[1];
        acc[10] += uv * w2[2]; acc[11] += uv * w2[3];
        acc[12] += uv * w3[0]; acc[13] += uv * w3[1];
        acc[14] += uv * w3[2]; acc[15] += uv * w3[3];
    }
    // packed store: row iL = i0+i fixed per thread; h = h0+hh, h>>4 = h0>>4
    const int iL = i0 + i;
    u16* __restrict__ dp = dstP
        + (((size_t)(iL >> 5) * 4 + (h0 >> 4)) << 9)   // (kb*4 + nb) * 512
        + ((iL >> 3) & 3) * 128                        // (lane>>4) * 16 * 8
        + (iL & 7);                                    // e
    #pragma unroll
    for (int hh = 0; hh < 16; ++hh)
        dp[hh * 8] = (u16)f2b(acc[hh]);                // (lane&15) * 8 step
}

// ---------------------------------------------------------------------------
// k_main: 1024 blocks, block (R,C) = (bx>>5, bx&31) owns adj tile
// [R*256,+256) x [C*256,+256). 8 panels of 32 rows x 256 cols, bf16,
// XOR chunk-swizzle (chunk' = (j>>3) ^ (row&7)), DOUBLE-buffered.
// Per panel: ds_write(p) -> issue loads(p+1) -> lgkmcnt(0) -> s_barrier ->
// compute(p). vmcnt never drained: next panel's loads overlap compute.
// Waves 0-1: top (16 rows each, full K=256, finished per panel -> wst[C]).
// Waves 2-3: bot (128 cols each, panel = K-chunk; accB persists -> wsb[R]).
// Fragment/swizzle math identical to R7 (harness-verified).
// ---------------------------------------------------------------------------
__global__ __launch_bounds__(256, 2) void k_main(
    const float* __restrict__ adj, const u16* __restrict__ ws,
    float* __restrict__ wst, float* __restrict__ wsb)
{
    __shared__ u16 P[2][32 * 256];    // double-buffered panel, swizzled

    const int bx = blockIdx.x;
    const int R0 = (bx >> 5) * 256, C0 = (bx & 31) * 256;
    const int t = threadIdx.x;
    const int w = t >> 6, l = t & 63;
    const int q = l >> 4, l15 = l & 15;
    const u16* __restrict__ BPl_u = ws + (size_t)l * 8;              // pu (bot)
    const u16* __restrict__ BPl_v = ws + PACK_SIDE + (size_t)l * 8;  // pv (top)
    // staging base: this wave stages rows w*8 .. w*8+8 of each panel
    const float* __restrict__ apw = adj + (size_t)(R0 + w * 8) * NROWS + C0 + l * 4;

    f32x4 accB[8][4];   // bot: 128 cols per bot-wave, persists across panels
    #pragma unroll
    for (int mt = 0; mt < 8; ++mt)
        #pragma unroll
        for (int nn = 0; nn < 4; ++nn) accB[mt][nn] = (f32x4){0.f, 0.f, 0.f, 0.f};

    // prologue: panel 0 rows into regs
    f32x4 reg[8];
    #pragma unroll
    for (int rr = 0; rr < 8; ++rr)
        reg[rr] = *(const f32x4*)(apw + (size_t)rr * NROWS);

    for (int p = 0; p < 8; ++p) {
        u16* __restrict__ Pb = P[p & 1];

        // ---- f2b + ds_write panel p (row&7 == rr since rows are w*8+rr) ----
        #pragma unroll
        for (int rr = 0; rr < 8; ++rr) {
            const int row = w * 8 + rr;
            s16x4 b;
            b[0] = f2b(reg[rr][0]); b[1] = f2b(reg[rr][1]);
            b[2] = f2b(reg[rr][2]); b[3] = f2b(reg[rr][3]);
            *(s16x4*)&Pb[row * 256 + (((l >> 1) ^ rr) << 3) + ((l & 1) << 2)] = b;
        }

        // ---- issue panel p+1 loads (stay in flight across the barrier) ----
        if (p < 7) {
            #pragma unroll
            for (int rr = 0; rr < 8; ++rr)
                reg[rr] = *(const f32x4*)(apw + (size_t)((p + 1) * 32 + rr) * NROWS);
        }

        asm volatile("s_waitcnt lgkmcnt(0)" ::: "memory");  // own ds_writes done
        __builtin_amdgcn_s_barrier();                       // all waves' writes done
        __builtin_amdgcn_sched_barrier(0);                  // no hoist above barrier

        if (w < 2) {
            // ---- top: rows p*32 + w*16 .. +16, full K=256 of this C-tile ----
            f32x4 accT[4];
            #pragma unroll
            for (int nn = 0; nn < 4; ++nn) accT[nn] = (f32x4){0.f, 0.f, 0.f, 0.f};
            const int rp = w * 16 + l15;
            #pragma unroll
            for (int kk = 0; kk < 8; ++kk) {
                const int kb = (C0 >> 5) + kk;
                s16x8 bf[4];
                #pragma unroll
                for (int nn = 0; nn < 4; ++nn)
                    bf[nn] = *(const s16x8*)(BPl_v + ((size_t)(kb * 4 + nn) << 9));
                s16x8 af = *(const s16x8*)&Pb[rp * 256 + (((kk * 4 + q) ^ (rp & 7)) << 3)];
                #pragma unroll
                for (int nn = 0; nn < 4; ++nn)
                    accT[nn] = __builtin_amdgcn_mfma_f32_16x16x32_bf16(
                        af, bf[nn], accT[nn], 0, 0, 0);
            }
            // stream finished 16 rows to ws_top[C][global row][h] (m89 C/D)
            float* __restrict__ WT = wst + (size_t)(bx & 31) * (NROWS * HID)
                                   + (size_t)(R0 + p * 32 + w * 16) * HID;
            #pragma unroll
            for (int nn = 0; nn < 4; ++nn)
                #pragma unroll
                for (int rg = 0; rg < 4; ++rg)
                    WT[(size_t)(q * 4 + rg) * HID + nn * 16 + l15] = accT[nn][rg];
        } else {
            // ---- bot: cols (w-2)*128..+128; panel p = K-chunk kb ----
            const int kb = (R0 >> 5) + p;
            s16x8 bf[4];
            #pragma unroll
            for (int nn = 0; nn < 4; ++nn)
                bf[nn] = *(const s16x8*)(BPl_u + ((size_t)(kb * 4 + nn) << 9));
            #pragma unroll
            for (int mt = 0; mt < 8; ++mt) {
                const int j = (w - 2) * 128 + mt * 16 + l15;
                s16x8 af;
                #pragma unroll
                for (int tt = 0; tt < 8; ++tt)
                    af[tt] = (short)Pb[(q * 8 + tt) * 256 + (((j >> 3) ^ tt) << 3) + (j & 7)];
                #pragma unroll
                for (int nn = 0; nn < 4; ++nn)
                    accB[mt][nn] = __builtin_amdgcn_mfma_f32_16x16x32_bf16(
                        af, bf[nn], accB[mt][nn], 0, 0, 0);
            }
        }
        // no second barrier: next iteration writes the OTHER buffer; writes to
        // THIS buffer (p+2) occur only after barrier(p+1) -> readers are done.
    }

    if (w >= 2) {
        // bot partial -> ws_bot[R][global col][h]
        float* __restrict__ WB = wsb + (size_t)(bx >> 5) * (NROWS * HID)
                               + (size_t)(C0 + (w - 2) * 128) * HID;
        #pragma unroll
        for (int mt = 0; mt < 8; ++mt)
            #pragma unroll
            for (int nn = 0; nn < 4; ++nn)
                #pragma unroll
                for (int rg = 0; rg < 4; ++rg)
                    WB[(size_t)(mt * 16 + q * 4 + rg) * HID + nn * 16 + l15] =
                        accB[mt][nn][rg];
    }
}

// ---------------------------------------------------------------------------
// k_fin: out[r] = degree[r] * sum_{c<32} ws[c][r][:] + bias. grid 1024:
// blocks 0..511 top (ws_top), 512..1023 bot (ws_bot); 16 rows per block.
// ---------------------------------------------------------------------------
__global__ __launch_bounds__(256, 4) void k_fin(
    const float* __restrict__ degree, const float* __restrict__ bias,
    const float* __restrict__ wst, const float* __restrict__ wsb,
    float* __restrict__ out)
{
    const int b = blockIdx.x;
    const int side = (b >= 512);
    const int t = threadIdx.x;
    const int r = (b & 511) * 16 + (t >> 4);
    const int c4 = (t & 15) * 4;
    const float* __restrict__ W = side ? wsb : wst;

    f32x4 s = (f32x4){0.f, 0.f, 0.f, 0.f};
    #pragma unroll
    for (int c = 0; c < 32; ++c)
        s += *(const f32x4*)&W[(size_t)c * (NROWS * HID) + (size_t)r * HID + c4];
    const int grow = side * NROWS + r;
    const float d = degree[grow];
    f32x4 bb = *(const f32x4*)&bias[c4];
    *(f32x4*)&out[(size_t)grow * HID + c4] = d * s + bb;
}

extern "C" void kernel_launch(void* const* d_in, const int* in_sizes, int n_in,
                              void* d_out, int out_size, void* d_ws, size_t ws_size,
                              hipStream_t stream) {
    (void)in_sizes; (void)n_in; (void)out_size; (void)ws_size;
    const float* u      = (const float*)d_in[0];
    const float* v      = (const float*)d_in[1];
    const float* adj    = (const float*)d_in[2];
    const float* degree = (const float*)d_in[3];
    const float* uw     = (const float*)d_in[4];
    const float* vw     = (const float*)d_in[5];
    const float* bias   = (const float*)d_in[6];
    const int*   rp     = (const int*)d_in[7];
    u16*   ws  = (u16*)d_ws;                      // [0,1MB): pu; [1MB,2MB): pv
    float* wst = (float*)(ws + 2 * PACK_SIDE);    // [2MB, 66MB): top partials
    float* wsb = wst + (size_t)32 * NROWS * HID;  // [66MB, 130MB): bot partials
    float* out = (float*)d_out;

    k_prep<<<dim3(128, 2), 256, 0, stream>>>(u, v, uw, vw, rp, ws);
    k_main<<<dim3(1024),   256, 0, stream>>>(adj, ws, wst, wsb);
    k_fin <<<dim3(1024),   256, 0, stream>>>(degree, bias, wst, wsb, out);
}

// Round 8
// 465.420 us; speedup vs baseline: 1.1849x; 1.1849x over previous
//
#include <hip/hip_runtime.h>
#include <stdint.h>

// GraphConvolution: out[0:8192]    = deg[i]     *(adj  @ (v@Wv)) + bias
//                   out[8192:16k]  = deg[8192+j]*(adjT @ (u@Wu)) + bias
// R5 (467us, best): packed-B + barrier-free K-split waves, reg-staged adj.
// R7/R9 (530/551): fused tiles, barrier or pipelined -- both 2.3 TB/s, all
// pipes idle. Diagnosis: register-staged adj loads serialize per-wave VMEM
// (load->waitcnt->use chains at VGPR=128); in-flight bytes collapse.
// R11: R5 structure + global_load_lds staging (fire-and-forget, no VGPR),
// per-wave double-buffered LDS tiles, counted vmcnt(8) (never 0 mid-loop),
// padded instr-groups (+32B/1KB) make both read patterns bank-conflict-free.

#define HID 64
#define IN_DIM 128
#define NROWS 8192
#define NCLS 5

typedef float f32x4 __attribute__((ext_vector_type(4)));
typedef short s16x8 __attribute__((ext_vector_type(8)));
typedef unsigned short u16;

// packed side size: 256 kb * 4 nb * 64 lane * 8 e = 524288 u16 = 1 MiB
#define PACK_SIDE 524288

static __device__ __forceinline__ short f2b(float x) {  // RNE fp32->bf16
    unsigned u = __builtin_bit_cast(unsigned, x);
    return (short)((u + 0x7FFFu + ((u >> 16) & 1u)) >> 16);
}

static __device__ __forceinline__ void gload16(const float* g, float* lds) {
    __builtin_amdgcn_global_load_lds(
        (const __attribute__((address_space(1))) void*)g,
        (__attribute__((address_space(3))) void*)lds, 16, 0, 0);
}

// ---------------------------------------------------------------------------
// k_prep: W = sum_{c<=r} weight[c]; s = X @ W; store B-fragment-packed bf16:
// pack[kb][nb][lane][e] = s[row = kb*32 + (lane>>4)*8 + e][h = nb*16 + (lane&15)]
// grid (128, 2): y=0 -> pu (from u), y=1 -> pv (from v). block 256.
// ---------------------------------------------------------------------------
__global__ __launch_bounds__(256, 2) void k_prep(
    const float* __restrict__ u, const float* __restrict__ v,
    const float* __restrict__ uw, const float* __restrict__ vw,
    const int* __restrict__ rp, u16* __restrict__ ws)
{
    __shared__ float W[IN_DIM * HID];
    __shared__ float X[64 * 129];

    const int y = blockIdx.y;
    const float* __restrict__ src  = y ? v  : u;
    const float* __restrict__ wsrc = y ? vw : uw;
    u16* __restrict__ dstP = ws + (size_t)y * PACK_SIDE;
    const int i0 = blockIdx.x * 64;
    const int t = threadIdx.x;
    int r = *rp; if (r > NCLS - 1) r = NCLS - 1; if (r < 0) r = 0;

    for (int idx = t; idx < IN_DIM * HID; idx += 256) {
        float s = 0.f;
        for (int c = 0; c <= r; ++c) s += wsrc[c * (IN_DIM * HID) + idx];
        W[idx] = s;
    }
    #pragma unroll
    for (int qq = 0; qq < 8; ++qq) {       // 64 rows x 32 float4 = 2048
        int idx = t + qq * 256;
        int row = idx >> 5, c4 = idx & 31;
        f32x4 val = *(const f32x4*)&src[(size_t)(i0 + row) * IN_DIM + c4 * 4];
        float* d = &X[row * 129 + c4 * 4];
        d[0] = val[0]; d[1] = val[1]; d[2] = val[2]; d[3] = val[3];
    }
    __syncthreads();

    const int i = t & 63, h0 = (t >> 6) * 16;
    float acc[16];
    #pragma unroll
    for (int k = 0; k < 16; ++k) acc[k] = 0.f;
    for (int c = 0; c < IN_DIM; ++c) {
        float uv = X[i * 129 + c];
        const f32x4* wr = (const f32x4*)&W[c * HID + h0];
        f32x4 w0 = wr[0], w1 = wr[1], w2 = wr[2], w3 = wr[3];
        acc[0]  += uv * w0[0]; acc[1]  += uv * w0[1];
        acc[2]  += uv * w0[2]; acc[3]  += uv * w0[3];
        acc[4]  += uv * w1[0]; acc[5]  += uv * w1[1];
        acc[6]  += uv * w1[2]; acc[7]  += uv * w1[3];
        acc[8]  += uv * w2[0]; acc[9]  += uv * w2[1];
        acc[10] += uv * w2[2]; acc[11] += uv * w2[3];
        acc[12] += uv * w3[0]; acc[13] += uv * w3[1];
        acc[14] += uv * w3[2]; acc[15] += uv * w3[3];
    }
    // packed store: row iL = i0+i fixed per thread; h = h0+hh, h>>4 = h0>>4
    const int iL = i0 + i;
    u16* __restrict__ dp = dstP
        + (((size_t)(iL >> 5) * 4 + (h0 >> 4)) << 9)   // (kb*4 + nb) * 512
        + ((iL >> 3) & 3) * 128                        // (lane>>4) * 16 * 8
        + (iL & 7);                                    // e
    #pragma unroll
    for (int hh = 0; hh < 16; ++hh)
        dp[hh * 8] = (u16)f2b(acc[hh]);                // (lane&15) * 8 step
}

// ---------------------------------------------------------------------------
// k_main: grid (256, 2), block 256 = 4 waves; wave w = K-quarter. Barrier-
// free K-loop; per-wave double-buffered LDS tile (8 gload_lds x 1KB, padded
// +8 floats per 256-float instr-group -> pitch 264). Per tau:
//   issue 8 packed-B loads -> issue 8 gload_lds(t+1) -> vmcnt(8) ->
//   ds_read fp32 + f2b + 16 MFMA.
// mode0 tile: [32 m-rows][64 k-cols]; mode1 tile: [64 k-rows][32 j-cols].
// Diagonal chunk order (a+tau / a-tau) pairs transpose partners for L3 dedup.
// Epilogue: per-wave partials -> LDS, reduce 4 K-quarters, degree+bias, out.
// ---------------------------------------------------------------------------
__global__ __launch_bounds__(256, 2) void k_main(
    const float* __restrict__ adj, const float* __restrict__ degree,
    const float* __restrict__ bias, const u16* __restrict__ ws,
    float* __restrict__ out)
{
    __shared__ float L[4][2][2112];   // per-wave dbuf tiles (8x264 each)

    const int mode = blockIdx.y;
    const int bx = blockIdx.x;
    const int t = threadIdx.x;
    const int w = t >> 6, l = t & 63;
    const int q = l >> 4, l15 = l & 15;
    const int m0 = bx * 32;
    const unsigned a = (unsigned)(bx >> 1);        // 64-wide chunk index
    const int kbase = w * 2048;
    // mode0 (top) consumes sv -> pv at PACK_SIDE; mode1 (bot) consumes su -> pu
    const u16* __restrict__ BP = ws + (mode == 0 ? (size_t)PACK_SIDE : 0);
    const u16* __restrict__ BPl = BP + (size_t)l * 8;  // lane-fixed sub-base
    float* __restrict__ Lw0 = &L[w][0][0];
    float* __restrict__ Lw1 = &L[w][1][0];

    f32x4 acc[2][4];
    #pragma unroll
    for (int i = 0; i < 2; ++i)
        #pragma unroll
        for (int j = 0; j < 4; ++j) acc[i][j] = (f32x4){0.f, 0.f, 0.f, 0.f};

    if (mode == 0) {
        // ---- top: C[m=row][n=h] = adj[row][:] . sv[:][h] ----
        const int sr = l >> 4, sc = l & 15;     // staging: 4 rows x 16 chunks
        const float* __restrict__ ab = adj + (size_t)m0 * NROWS + sc * 4;
        // prologue: tile 0 -> buf0
        {
            const int k0 = kbase + (int)((a & 31u) << 6);
            #pragma unroll
            for (int i = 0; i < 8; ++i)
                gload16(ab + (size_t)(i * 4 + sr) * NROWS + k0, Lw0 + i * 264);
        }
        #pragma unroll 2
        for (int tau = 0; tau < 32; ++tau) {
            const int k0c = kbase + (int)(((a + tau) & 31u) << 6);
            const int kb0 = k0c >> 5;
            // packed-B for this tau (issued BEFORE next-tile gloads)
            s16x8 bf0[4], bf1[4];
            #pragma unroll
            for (int nn = 0; nn < 4; ++nn)
                bf0[nn] = *(const s16x8*)(BPl + ((size_t)(kb0 * 4 + nn) << 9));
            #pragma unroll
            for (int nn = 0; nn < 4; ++nn)
                bf1[nn] = *(const s16x8*)(BPl + ((size_t)((kb0 + 1) * 4 + nn) << 9));
            // stage tile tau+1 into other buffer
            if (tau < 31) {
                const int k0n = kbase + (int)(((a + tau + 1) & 31u) << 6);
                float* Ln = (tau & 1) ? Lw0 : Lw1;
                #pragma unroll
                for (int i = 0; i < 8; ++i)
                    gload16(ab + (size_t)(i * 4 + sr) * NROWS + k0n, Ln + i * 264);
                asm volatile("s_waitcnt vmcnt(8)" ::: "memory");
            } else {
                asm volatile("s_waitcnt vmcnt(0)" ::: "memory");
            }
            __builtin_amdgcn_sched_barrier(0);
            const float* __restrict__ Lb = (tau & 1) ? Lw1 : Lw0;
            #pragma unroll
            for (int kh = 0; kh < 2; ++kh) {
                #pragma unroll
                for (int mt = 0; mt < 2; ++mt) {
                    const int row = mt * 16 + l15;
                    const int base = (row >> 2) * 264 + (row & 3) * 64 + (kh * 8 + q * 2) * 4;
                    f32x4 lo = *(const f32x4*)&Lb[base];
                    f32x4 hi = *(const f32x4*)&Lb[base + 4];
                    s16x8 af;
                    af[0]=f2b(lo[0]); af[1]=f2b(lo[1]); af[2]=f2b(lo[2]); af[3]=f2b(lo[3]);
                    af[4]=f2b(hi[0]); af[5]=f2b(hi[1]); af[6]=f2b(hi[2]); af[7]=f2b(hi[3]);
                    #pragma unroll
                    for (int nn = 0; nn < 4; ++nn)
                        acc[mt][nn] = __builtin_amdgcn_mfma_f32_16x16x32_bf16(
                            af, kh ? bf1[nn] : bf0[nn], acc[mt][nn], 0, 0, 0);
                }
            }
        }
    } else {
        // ---- bot: C[m=col j][n=h] = sum_i adj[i][j]*su[i][h] ----
        const int sr = l >> 3, sc = l & 7;      // staging: 8 rows x 8 chunks
        const float* __restrict__ ab = adj + (size_t)sr * NROWS + m0 + sc * 4;
        // prologue: tile 0 -> buf0
        {
            const int i00 = kbase + (int)((a & 31u) << 6);
            #pragma unroll
            for (int i = 0; i < 8; ++i)
                gload16(ab + (size_t)(i00 + i * 8) * NROWS, Lw0 + i * 264);
        }
        #pragma unroll 2
        for (int tau = 0; tau < 32; ++tau) {
            const int i0c = kbase + (int)(((a - tau) & 31u) << 6);
            const int kb0 = i0c >> 5;
            s16x8 bf0[4], bf1[4];
            #pragma unroll
            for (int nn = 0; nn < 4; ++nn)
                bf0[nn] = *(const s16x8*)(BPl + ((size_t)(kb0 * 4 + nn) << 9));
            #pragma unroll
            for (int nn = 0; nn < 4; ++nn)
                bf1[nn] = *(const s16x8*)(BPl + ((size_t)((kb0 + 1) * 4 + nn) << 9));
            if (tau < 31) {
                const int i0n = kbase + (int)(((a - tau - 1) & 31u) << 6);
                float* Ln = (tau & 1) ? Lw0 : Lw1;
                #pragma unroll
                for (int i = 0; i < 8; ++i)
                    gload16(ab + (size_t)(i0n + i * 8) * NROWS, Ln + i * 264);
                asm volatile("s_waitcnt vmcnt(8)" ::: "memory");
            } else {
                asm volatile("s_waitcnt vmcnt(0)" ::: "memory");
            }
            __builtin_amdgcn_sched_barrier(0);
            const float* __restrict__ Lb = (tau & 1) ? Lw1 : Lw0;
            #pragma unroll
            for (int kh = 0; kh < 2; ++kh) {
                #pragma unroll
                for (int mt = 0; mt < 2; ++mt) {
                    const int j = mt * 16 + l15;
                    const int gbase = (kh * 4 + q) * 264 + j;
                    s16x8 af;
                    #pragma unroll
                    for (int tt = 0; tt < 8; ++tt)
                        af[tt] = f2b(Lb[gbase + tt * 32]);
                    #pragma unroll
                    for (int nn = 0; nn < 4; ++nn)
                        acc[mt][nn] = __builtin_amdgcn_mfma_f32_16x16x32_bf16(
                            af, kh ? bf1[nn] : bf0[nn], acc[mt][nn], 0, 0, 0);
                }
            }
        }
    }

    // partials -> own LDS region (C/D layout: col=l15, row=q*4+reg; m89)
    asm volatile("" ::: "memory");
    {
        float* __restrict__ P = &L[w][0][0];
        #pragma unroll
        for (int mt = 0; mt < 2; ++mt)
            #pragma unroll
            for (int nn = 0; nn < 4; ++nn)
                #pragma unroll
                for (int rg = 0; rg < 4; ++rg)
                    P[(mt * 16 + q * 4 + rg) * 64 + nn * 16 + l15] = acc[mt][nn][rg];
    }
    __syncthreads();

    // reduce 4 K-splits, scale + bias, coalesced f32x4 stores
    const int e0 = t * 8;
    const int m = e0 >> 6, n = e0 & 63;
    f32x4 s0 = (f32x4){0.f,0.f,0.f,0.f}, s1 = s0;
    #pragma unroll
    for (int ww = 0; ww < 4; ++ww) {
        const float* __restrict__ S = &L[ww][0][0];
        s0 += *(const f32x4*)&S[e0];
        s1 += *(const f32x4*)&S[e0 + 4];
    }
    const int grow = (mode ? NROWS : 0) + m0 + m;
    const float d = degree[grow];
    f32x4 b0 = *(const f32x4*)&bias[n];
    f32x4 b1 = *(const f32x4*)&bias[n + 4];
    f32x4 o0 = d * s0 + b0;
    f32x4 o1 = d * s1 + b1;
    *(f32x4*)&out[(size_t)grow * HID + n]     = o0;
    *(f32x4*)&out[(size_t)grow * HID + n + 4] = o1;
}

extern "C" void kernel_launch(void* const* d_in, const int* in_sizes, int n_in,
                              void* d_out, int out_size, void* d_ws, size_t ws_size,
                              hipStream_t stream) {
    (void)in_sizes; (void)n_in; (void)out_size; (void)ws_size;
    const float* u      = (const float*)d_in[0];
    const float* v      = (const float*)d_in[1];
    const float* adj    = (const float*)d_in[2];
    const float* degree = (const float*)d_in[3];
    const float* uw     = (const float*)d_in[4];
    const float* vw     = (const float*)d_in[5];
    const float* bias   = (const float*)d_in[6];
    const int*   rp     = (const int*)d_in[7];
    u16*   ws  = (u16*)d_ws;     // [0,1MB): pu packed; [1MB,2MB): pv packed
    float* out = (float*)d_out;

    k_prep<<<dim3(128, 2), 256, 0, stream>>>(u, v, uw, vw, rp, ws);
    k_main<<<dim3(256, 2), 256, 0, stream>>>(adj, degree, bias, ws, out);
}